// Round 2
// baseline (855.059 us; speedup 1.0000x reference)
//
#include <hip/hip_runtime.h>

typedef _Float16 half8_t __attribute__((ext_vector_type(8)));
typedef _Float16 half4_t __attribute__((ext_vector_type(4)));
typedef float f32x4 __attribute__((ext_vector_type(4)));

#define MFMA16(a, b, c) __builtin_amdgcn_mfma_f32_16x16x32_f16((a), (b), (c), 0, 0, 0)

typedef const unsigned int __attribute__((address_space(1)))* gas_ptr;
typedef unsigned int __attribute__((address_space(3)))* las_ptr;

__device__ __forceinline__ void gload16(const void* g, void* l) {
    __builtin_amdgcn_global_load_lds((gas_ptr)g, (las_ptr)l, 16, 0, 0);
}

// ---------------- convert / transpose ----------------

__global__ void cvt_f2h_kernel(const float* __restrict__ in, _Float16* __restrict__ out, int n4) {
    int stride = gridDim.x * blockDim.x;
    for (int i = blockIdx.x * blockDim.x + threadIdx.x; i < n4; i += stride) {
        f32x4 v = *(const f32x4*)(in + (size_t)4 * i);
        half4_t h;
        h[0] = (_Float16)v[0]; h[1] = (_Float16)v[1];
        h[2] = (_Float16)v[2]; h[3] = (_Float16)v[3];
        *(half4_t*)(out + (size_t)4 * i) = h;
    }
}

// out[j][k] = in[k][j], K fixed at 768
__global__ void transpose768_kernel(const float* __restrict__ in, _Float16* __restrict__ out, int ncols) {
    int idx = blockIdx.x * 256 + threadIdx.x;
    int total = ncols * 768;
    if (idx < total) {
        int j = idx / 768;
        int k = idx - j * 768;
        out[idx] = (_Float16)in[(size_t)k * ncols + j];
    }
}

// ---------------- GEMM core: 128x128 tile, BK=64, 4 waves, global_load_lds staging ----------------
// A: [M][768] f16 row-major (K contiguous); Bt: [Nout][768] f16 (K contiguous)
// LDS: linear [128][64] f16 (128 B rows) per operand — required by global_load_lds
//      (wave-uniform base + lane*16 dest; no padding allowed).

__device__ __forceinline__ void run_gemm(const _Float16* __restrict__ A,
                                         const _Float16* __restrict__ Bt,
                                         int mbase, int nbase,
                                         _Float16* As, _Float16* Bs,
                                         f32x4 (&acc)[4][4]) {
    const int tid = threadIdx.x;
    const int lane = tid & 63;
    const int wave = tid >> 6;
    const int wm = (wave >> 1) * 64;
    const int wn = (wave & 1) * 64;
    const int l15 = lane & 15;
    const int l4 = lane >> 4;
    const int rl = lane >> 3;        // row within 8-row chunk
    const int cs = (lane & 7) * 8;   // col element offset

    #pragma unroll
    for (int mi = 0; mi < 4; ++mi)
        #pragma unroll
        for (int ni = 0; ni < 4; ++ni)
            acc[mi][ni] = (f32x4){0.f, 0.f, 0.f, 0.f};

    const _Float16* Abase = A + (size_t)mbase * 768;
    const _Float16* Bbase = Bt + (size_t)nbase * 768;

    for (int kt = 0; kt < 12; ++kt) {
        const int kof = kt * 64;
        // stage 128x64 A and B tiles: 16 chunks each of 8 rows x 64 cols (1024 B);
        // wave w issues chunks w*4..w*4+3 per operand.
        #pragma unroll
        for (int i = 0; i < 4; ++i) {
            int row = wave * 32 + i * 8 + rl;
            gload16(Abase + (size_t)row * 768 + kof + cs, (char*)As + (wave * 4 + i) * 1024);
            gload16(Bbase + (size_t)row * 768 + kof + cs, (char*)Bs + (wave * 4 + i) * 1024);
        }
        __syncthreads();
        #pragma unroll
        for (int kk = 0; kk < 64; kk += 32) {
            half8_t a[4], b[4];
            #pragma unroll
            for (int mi = 0; mi < 4; ++mi)
                a[mi] = *(const half8_t*)(As + (wm + mi * 16 + l15) * 64 + kk + l4 * 8);
            #pragma unroll
            for (int ni = 0; ni < 4; ++ni)
                b[ni] = *(const half8_t*)(Bs + (wn + ni * 16 + l15) * 64 + kk + l4 * 8);
            #pragma unroll
            for (int mi = 0; mi < 4; ++mi)
                #pragma unroll
                for (int ni = 0; ni < 4; ++ni)
                    acc[mi][ni] = MFMA16(a[mi], b[ni], acc[mi][ni]);
        }
        __syncthreads();
    }
}

// GEMM1: qkv = x @ w_qkv, epilogue: +pos_enc (k), relu (q,k), scatter to head layout
__global__ __launch_bounds__(256) void gemm_qkv_kernel(
    const _Float16* __restrict__ xh, const _Float16* __restrict__ wqkvT,
    const float* __restrict__ pos_enc,
    _Float16* __restrict__ qh, _Float16* __restrict__ kh, _Float16* __restrict__ vh) {
    __shared__ _Float16 As[128 * 64];
    __shared__ _Float16 Bs[128 * 64];
    int bid = blockIdx.x;
    int mtile = bid / 18, ntile = bid - mtile * 18;
    f32x4 acc[4][4];
    run_gemm(xh, wqkvT, mtile * 128, ntile * 128, As, Bs, acc);

    const int tid = threadIdx.x;
    const int lane = tid & 63;
    const int wave = tid >> 6;
    const int wm = (wave >> 1) * 64;
    const int wn = (wave & 1) * 64;
    const int l15 = lane & 15;
    const int l4 = lane >> 4;

    #pragma unroll
    for (int mi = 0; mi < 4; ++mi) {
        #pragma unroll
        for (int ni = 0; ni < 4; ++ni) {
            int gc = ntile * 128 + wn + ni * 16 + l15;
            int s = gc / 768;
            int c = gc - s * 768;
            int h = c >> 6, d = c & 63;
            _Float16* dst = (s == 0) ? qh : ((s == 1) ? kh : vh);
            #pragma unroll
            for (int r = 0; r < 4; ++r) {
                int gr = mtile * 128 + wm + mi * 16 + l4 * 4 + r;
                int b = gr / 196;
                int n = gr - b * 196;
                float v = acc[mi][ni][r];
                if (s == 1) v += pos_enc[n * 768 + c];
                if (s < 2) v = fmaxf(v, 0.f);
                dst[((size_t)(b * 12 + h) * 196 + n) * 64 + d] = (_Float16)v;
            }
        }
    }
}

// GEMM2: out = fused @ w_proj + b_proj (f32 out)
__global__ __launch_bounds__(256) void gemm_proj_kernel(
    const _Float16* __restrict__ fused, const _Float16* __restrict__ wprojT,
    const float* __restrict__ b_proj, float* __restrict__ out) {
    __shared__ _Float16 As[128 * 64];
    __shared__ _Float16 Bs[128 * 64];
    int bid = blockIdx.x;
    int mtile = bid / 6, ntile = bid - mtile * 6;
    f32x4 acc[4][4];
    run_gemm(fused, wprojT, mtile * 128, ntile * 128, As, Bs, acc);

    const int tid = threadIdx.x;
    const int lane = tid & 63;
    const int wave = tid >> 6;
    const int wm = (wave >> 1) * 64;
    const int wn = (wave & 1) * 64;
    const int l15 = lane & 15;
    const int l4 = lane >> 4;

    #pragma unroll
    for (int mi = 0; mi < 4; ++mi) {
        #pragma unroll
        for (int ni = 0; ni < 4; ++ni) {
            int gc = ntile * 128 + wn + ni * 16 + l15;
            float bp = b_proj[gc];
            #pragma unroll
            for (int r = 0; r < 4; ++r) {
                int gr = mtile * 128 + wm + mi * 16 + l4 * 4 + r;
                out[(size_t)gr * 768 + gc] = acc[mi][ni][r] + bp;
            }
        }
    }
}

// ---------------- attention part 1: kv = k^T v (64x64), ksum, z ----------------
__global__ __launch_bounds__(512) void attn1_kernel(
    const _Float16* __restrict__ qh, const _Float16* __restrict__ kh,
    const _Float16* __restrict__ vh, _Float16* __restrict__ kvg, float* __restrict__ zg) {
    __shared__ _Float16 k_t[64 * 232];
    __shared__ _Float16 v_t[64 * 232];
    __shared__ float ksum_p[8 * 64];
    __shared__ float ksum[64];

    int bh = blockIdx.x;
    int tid = threadIdx.x;
    int lane = tid & 63, wave = tid >> 6;
    int l15 = lane & 15, l4 = lane >> 4;
    size_t base = (size_t)bh * 12544;

    // zero pad columns [196,232)
    for (int idx = tid; idx < 1152; idx += 512) {
        int c = idx / 18, u = idx - c * 18;
        ((unsigned int*)(k_t + c * 232 + 196))[u] = 0u;
        ((unsigned int*)(v_t + c * 232 + 196))[u] = 0u;
    }
    // load + transpose k, v
    for (int j = tid; j < 3136; j += 512) {
        int e = j * 4, n = e >> 6, c = e & 63;
        half4_t kq = *(const half4_t*)(kh + base + e);
        half4_t vq = *(const half4_t*)(vh + base + e);
        k_t[(c + 0) * 232 + n] = kq[0]; k_t[(c + 1) * 232 + n] = kq[1];
        k_t[(c + 2) * 232 + n] = kq[2]; k_t[(c + 3) * 232 + n] = kq[3];
        v_t[(c + 0) * 232 + n] = vq[0]; v_t[(c + 1) * 232 + n] = vq[1];
        v_t[(c + 2) * 232 + n] = vq[2]; v_t[(c + 3) * 232 + n] = vq[3];
    }
    __syncthreads();

    // kv MFMA: wave -> (ct, dt0), (ct, dt0+1)
    int ct = wave >> 1, dt0 = (wave & 1) * 2;
    f32x4 acc0 = {0.f, 0.f, 0.f, 0.f}, acc1 = {0.f, 0.f, 0.f, 0.f};
    #pragma unroll
    for (int ks = 0; ks < 7; ++ks) {
        half8_t a  = *(const half8_t*)(k_t + (ct * 16 + l15) * 232 + ks * 32 + l4 * 8);
        half8_t b0 = *(const half8_t*)(v_t + (dt0 * 16 + l15) * 232 + ks * 32 + l4 * 8);
        half8_t b1 = *(const half8_t*)(v_t + (dt0 * 16 + 16 + l15) * 232 + ks * 32 + l4 * 8);
        acc0 = MFMA16(a, b0, acc0);
        acc1 = MFMA16(a, b1, acc1);
    }
    {
        half4_t h0, h1;
        #pragma unroll
        for (int r = 0; r < 4; ++r) { h0[r] = (_Float16)acc0[r]; h1[r] = (_Float16)acc1[r]; }
        // store kv transposed: kvg[d][c]
        *(half4_t*)(kvg + (size_t)bh * 4096 + (dt0 * 16 + l15) * 64 + ct * 16 + l4 * 4) = h0;
        *(half4_t*)(kvg + (size_t)bh * 4096 + ((dt0 + 1) * 16 + l15) * 64 + ct * 16 + l4 * 4) = h1;
    }
    // ksum partials
    {
        int n0 = wave * 25;
        int n1 = (n0 + 25 < 196) ? (n0 + 25) : 196;
        float s = 0.f;
        for (int n = n0; n < n1; ++n) s += (float)k_t[lane * 232 + n];
        ksum_p[wave * 64 + lane] = s;
    }
    __syncthreads();
    if (tid < 64) {
        float s = 0.f;
        #pragma unroll
        for (int w = 0; w < 8; ++w) s += ksum_p[w * 64 + tid];
        ksum[tid] = s;
    }
    __syncthreads();
    if (tid < 196) {
        const _Float16* qrow = qh + base + tid * 64;
        float s = 0.f;
        #pragma unroll
        for (int c = 0; c < 64; ++c) s += (float)qrow[c] * ksum[c];
        zg[(size_t)bh * 196 + tid] = 1.0f / (s + 1e-6f);
    }
}

// ---------------- attention part 2: out = z*(q@kv) + dwconv(v), write fused ----------------
#define LDK 72
__global__ __launch_bounds__(512) void attn2_kernel(
    const _Float16* __restrict__ qh, const _Float16* __restrict__ vh,
    const _Float16* __restrict__ kvg, const float* __restrict__ zg,
    const float* __restrict__ dwc_w, const float* __restrict__ dwc_b,
    _Float16* __restrict__ fused) {
    __shared__ _Float16 q_l[208 * LDK];
    __shared__ _Float16 v_n[196 * 64];

    int bh = blockIdx.x;
    int bb = bh / 12, hh = bh - bb * 12;
    int tid = threadIdx.x;
    int lane = tid & 63, wave = tid >> 6;
    int l15 = lane & 15, l4 = lane >> 4;
    size_t base = (size_t)bh * 12544;

    // zero q pad rows [196,208)
    for (int i = tid; i < 432; i += 512) ((unsigned int*)(q_l + 196 * LDK))[i] = 0u;
    for (int j = tid; j < 3136; j += 512) {
        int e = j * 4, n = e >> 6, c = e & 63;
        *(half4_t*)(q_l + n * LDK + c) = *(const half4_t*)(qh + base + e);
        *(half4_t*)(v_n + e) = *(const half4_t*)(vh + base + e);
    }
    __syncthreads();

    for (int t = wave; t < 52; t += 8) {
        int mt = t >> 2, dt = t & 3;
        int d = dt * 16 + l15;
        f32x4 acc = {0.f, 0.f, 0.f, 0.f};
        half8_t a0 = *(const half8_t*)(q_l + (mt * 16 + l15) * LDK + l4 * 8);
        half8_t a1 = *(const half8_t*)(q_l + (mt * 16 + l15) * LDK + 32 + l4 * 8);
        half8_t b0 = *(const half8_t*)(kvg + (size_t)bh * 4096 + d * 64 + l4 * 8);
        half8_t b1 = *(const half8_t*)(kvg + (size_t)bh * 4096 + d * 64 + 32 + l4 * 8);
        acc = MFMA16(a0, b0, acc);
        acc = MFMA16(a1, b1, acc);

        float bd = dwc_b[d];
        float wc[25];
        #pragma unroll
        for (int j2 = 0; j2 < 25; ++j2) wc[j2] = dwc_w[d * 25 + j2];

        #pragma unroll
        for (int r = 0; r < 4; ++r) {
            int i = mt * 16 + l4 * 4 + r;
            if (i < 196) {
                int y = i / 14, x2 = i - y * 14;
                float cacc = bd;
                #pragma unroll
                for (int ky = 0; ky < 5; ++ky) {
                    int yy = y + ky - 2;
                    bool oky = (unsigned)yy < 14u;
                    #pragma unroll
                    for (int kx = 0; kx < 5; ++kx) {
                        int xx = x2 + kx - 2;
                        if (oky && (unsigned)xx < 14u)
                            cacc += (float)v_n[(yy * 14 + xx) * 64 + d] * wc[ky * 5 + kx];
                    }
                }
                float res = acc[r] * zg[(size_t)bh * 196 + i] + cacc;
                fused[((size_t)bb * 196 + i) * 768 + hh * 64 + d] = (_Float16)res;
            }
        }
    }
}

// ---------------- launcher ----------------

extern "C" void kernel_launch(void* const* d_in, const int* in_sizes, int n_in,
                              void* d_out, int out_size, void* d_ws, size_t ws_size,
                              hipStream_t stream) {
    const float* x       = (const float*)d_in[0];
    const float* w_qkv   = (const float*)d_in[1];
    const float* pos_enc = (const float*)d_in[2];
    const float* dwc_w   = (const float*)d_in[3];
    const float* dwc_b   = (const float*)d_in[4];
    const float* w_proj  = (const float*)d_in[5];
    const float* b_proj  = (const float*)d_in[6];

    const size_t NEEDED = 340574208;
    if (ws_size < NEEDED) return;  // insufficient scratch; bail (output stays poisoned)

    char* ws = (char*)d_ws;
    _Float16* xh     = (_Float16*)(ws + 0);          // 77,070,336 B (also 'fused' later)
    _Float16* fused  = xh;
    _Float16* wqkvT  = (_Float16*)(ws + 77070336);   // 3,538,944
    _Float16* wprojT = (_Float16*)(ws + 80609280);   // 1,179,648
    _Float16* qh     = (_Float16*)(ws + 81788928);   // 77,070,336
    _Float16* kh     = (_Float16*)(ws + 158859264);  // 77,070,336
    _Float16* vh     = (_Float16*)(ws + 235929600);  // 77,070,336
    _Float16* kvg    = (_Float16*)(ws + 312999936);  // 25,165,824
    float*    zg     = (float*)(ws + 338165760);     // 2,408,448

    cvt_f2h_kernel<<<4096, 256, 0, stream>>>(x, xh, 9633792);
    transpose768_kernel<<<(2304 * 768 + 255) / 256, 256, 0, stream>>>(w_qkv, wqkvT, 2304);
    transpose768_kernel<<<(768 * 768 + 255) / 256, 256, 0, stream>>>(w_proj, wprojT, 768);
    gemm_qkv_kernel<<<392 * 18, 256, 0, stream>>>(xh, wqkvT, pos_enc, qh, kh, vh);
    attn1_kernel<<<3072, 512, 0, stream>>>(qh, kh, vh, kvg, zg);
    attn2_kernel<<<3072, 512, 0, stream>>>(qh, vh, kvg, zg, dwc_w, dwc_b, fused);
    gemm_proj_kernel<<<392 * 6, 256, 0, stream>>>(fused, wprojT, b_proj, (float*)d_out);
}

// Round 3
// 835.664 us; speedup vs baseline: 1.0232x; 1.0232x over previous
//
#include <hip/hip_runtime.h>

typedef _Float16 half8_t __attribute__((ext_vector_type(8)));
typedef _Float16 half4_t __attribute__((ext_vector_type(4)));
typedef float f32x4 __attribute__((ext_vector_type(4)));

#define MFMA16(a, b, c) __builtin_amdgcn_mfma_f32_16x16x32_f16((a), (b), (c), 0, 0, 0)

typedef const unsigned int __attribute__((address_space(1)))* gas_ptr;
typedef unsigned int __attribute__((address_space(3)))* las_ptr;

__device__ __forceinline__ void gload16(const void* g, void* l) {
    __builtin_amdgcn_global_load_lds((gas_ptr)g, (las_ptr)l, 16, 0, 0);
}

// ---------------- convert / transpose ----------------

__global__ void cvt_f2h_kernel(const float* __restrict__ in, _Float16* __restrict__ out, int n4) {
    int stride = gridDim.x * blockDim.x;
    for (int i = blockIdx.x * blockDim.x + threadIdx.x; i < n4; i += stride) {
        f32x4 v = *(const f32x4*)(in + (size_t)4 * i);
        half4_t h;
        h[0] = (_Float16)v[0]; h[1] = (_Float16)v[1];
        h[2] = (_Float16)v[2]; h[3] = (_Float16)v[3];
        *(half4_t*)(out + (size_t)4 * i) = h;
    }
}

// out[j][k] = in[k][j], K fixed at 768
__global__ void transpose768_kernel(const float* __restrict__ in, _Float16* __restrict__ out, int ncols) {
    int idx = blockIdx.x * 256 + threadIdx.x;
    int total = ncols * 768;
    if (idx < total) {
        int j = idx / 768;
        int k = idx - j * 768;
        out[idx] = (_Float16)in[(size_t)k * ncols + j];
    }
}

// ---------------- GEMM core: 256x256 tile, BK=64, 8 waves (2Mx4N), dbuf gload_lds ----------------
// A: [M][768] f16 (K contiguous); Bt: [Nout][768] f16 (K contiguous)
// LDS per operand per buffer: linear [256][64] f16 (128 B rows), 32 KiB.
// XOR swizzle (both-sides, rule #21): LDS[r][slot s] holds G[r][s ^ (r&7)]
//   - staged via pre-swizzled global source (dest stays linear for gload_lds)
//   - frag reads XOR the slot with row&7 -> 8 lanes span all 32 banks (2-way = free)

__device__ __forceinline__ void run_gemm256(const _Float16* __restrict__ A,
                                            const _Float16* __restrict__ Bt,
                                            int mbase, int nbase,
                                            _Float16* As, _Float16* Bs,  // [2][16384] each
                                            f32x4 (&acc)[8][4]) {
    const int tid = threadIdx.x;
    const int lane = tid & 63;
    const int wave = tid >> 6;
    const int wr = wave >> 2;        // 0..1  (M half)
    const int wc = wave & 3;         // 0..3  (N quarter)
    const int l15 = lane & 15;
    const int l4 = lane >> 4;
    const int rl = lane >> 3;                      // staging row-in-chunk 0..7
    const int cs = ((lane & 7) ^ rl) * 8;          // pre-swizzled source col (elements)
    const int sx = l15 & 7;                        // read-side swizzle key

    #pragma unroll
    for (int mi = 0; mi < 8; ++mi)
        #pragma unroll
        for (int ni = 0; ni < 4; ++ni)
            acc[mi][ni] = (f32x4){0.f, 0.f, 0.f, 0.f};

    const _Float16* Abase = A + (size_t)mbase * 768;
    const _Float16* Bbase = Bt + (size_t)nbase * 768;

    // stage K-tile kt into buffer buf: 256x64 f16 per operand = 4 gload16/thread each
    #define STAGE256(buf, kof)                                                          \
        {                                                                               \
            _Float16* Ad = As + (buf) * 16384;                                          \
            _Float16* Bd = Bs + (buf) * 16384;                                          \
            _Pragma("unroll")                                                           \
            for (int i = 0; i < 4; ++i) {                                               \
                int row = i * 64 + wave * 8 + rl;                                       \
                gload16(Abase + (size_t)row * 768 + (kof) + cs,                         \
                        (char*)Ad + i * 8192 + wave * 1024);                            \
                gload16(Bbase + (size_t)row * 768 + (kof) + cs,                         \
                        (char*)Bd + i * 8192 + wave * 1024);                            \
            }                                                                           \
        }

    STAGE256(0, 0)
    __syncthreads();

    int cur = 0;
    for (int kt = 0; kt < 12; ++kt) {
        if (kt + 1 < 12) STAGE256(cur ^ 1, (kt + 1) * 64)

        const _Float16* Ac = As + cur * 16384;
        const _Float16* Bc = Bs + cur * 16384;
        #pragma unroll
        for (int ks = 0; ks < 2; ++ks) {
            half8_t b[4];
            #pragma unroll
            for (int ni = 0; ni < 4; ++ni)
                b[ni] = *(const half8_t*)(Bc + (wc * 64 + ni * 16 + l15) * 64 +
                                          (((ks * 4 + l4) ^ sx) << 3));
            #pragma unroll
            for (int mi = 0; mi < 8; ++mi) {
                half8_t a = *(const half8_t*)(Ac + (wr * 128 + mi * 16 + l15) * 64 +
                                              (((ks * 4 + l4) ^ sx) << 3));
                #pragma unroll
                for (int ni = 0; ni < 4; ++ni)
                    acc[mi][ni] = MFMA16(a, b[ni], acc[mi][ni]);
            }
        }
        __syncthreads();
        cur ^= 1;
    }
    #undef STAGE256
}

// GEMM1: qkv = x @ w_qkv, epilogue: +pos_enc (k), relu (q,k), scatter to head layout
__global__ __launch_bounds__(512, 2) void gemm_qkv_kernel(
    const _Float16* __restrict__ xh, const _Float16* __restrict__ wqkvT,
    const float* __restrict__ pos_enc,
    _Float16* __restrict__ qh, _Float16* __restrict__ kh, _Float16* __restrict__ vh) {
    __shared__ _Float16 As[2][16384];
    __shared__ _Float16 Bs[2][16384];
    int bid = blockIdx.x;
    int mtile = bid / 9, ntile = bid - mtile * 9;
    f32x4 acc[8][4];
    run_gemm256(xh, wqkvT, mtile * 256, ntile * 256, &As[0][0], &Bs[0][0], acc);

    const int tid = threadIdx.x;
    const int lane = tid & 63;
    const int wave = tid >> 6;
    const int wr = wave >> 2;
    const int wc = wave & 3;
    const int l15 = lane & 15;
    const int l4 = lane >> 4;

    // 768 = 3*256: all 256 columns of this block live in one q/k/v segment
    const int s = ntile / 3;
    const int cb = (ntile - s * 3) * 256 + wc * 64;
    _Float16* dst = (s == 0) ? qh : ((s == 1) ? kh : vh);

    #pragma unroll
    for (int mi = 0; mi < 8; ++mi) {
        #pragma unroll
        for (int ni = 0; ni < 4; ++ni) {
            int c = cb + ni * 16 + l15;
            int h = c >> 6, d = c & 63;
            #pragma unroll
            for (int r = 0; r < 4; ++r) {
                int gr = mtile * 256 + wr * 128 + mi * 16 + l4 * 4 + r;
                int b = gr / 196;
                int n = gr - b * 196;
                float v = acc[mi][ni][r];
                if (s == 1) v += pos_enc[n * 768 + c];
                if (s < 2) v = fmaxf(v, 0.f);
                dst[((size_t)(b * 12 + h) * 196 + n) * 64 + d] = (_Float16)v;
            }
        }
    }
}

// GEMM2: out = fused @ w_proj + b_proj (f32 out)
__global__ __launch_bounds__(512, 2) void gemm_proj_kernel(
    const _Float16* __restrict__ fused, const _Float16* __restrict__ wprojT,
    const float* __restrict__ b_proj, float* __restrict__ out) {
    __shared__ _Float16 As[2][16384];
    __shared__ _Float16 Bs[2][16384];
    int bid = blockIdx.x;
    int mtile = bid / 3, ntile = bid - mtile * 3;
    f32x4 acc[8][4];
    run_gemm256(fused, wprojT, mtile * 256, ntile * 256, &As[0][0], &Bs[0][0], acc);

    const int tid = threadIdx.x;
    const int lane = tid & 63;
    const int wave = tid >> 6;
    const int wr = wave >> 2;
    const int wc = wave & 3;
    const int l15 = lane & 15;
    const int l4 = lane >> 4;

    #pragma unroll
    for (int mi = 0; mi < 8; ++mi) {
        #pragma unroll
        for (int ni = 0; ni < 4; ++ni) {
            int gc = ntile * 256 + wc * 64 + ni * 16 + l15;
            float bp = b_proj[gc];
            #pragma unroll
            for (int r = 0; r < 4; ++r) {
                int gr = mtile * 256 + wr * 128 + mi * 16 + l4 * 4 + r;
                out[(size_t)gr * 768 + gc] = acc[mi][ni][r] + bp;
            }
        }
    }
}

// ---------------- attention part 1: kv = k^T v (64x64), ksum, z ----------------
__global__ __launch_bounds__(512) void attn1_kernel(
    const _Float16* __restrict__ qh, const _Float16* __restrict__ kh,
    const _Float16* __restrict__ vh, _Float16* __restrict__ kvg, float* __restrict__ zg) {
    __shared__ _Float16 k_t[64 * 232];
    __shared__ _Float16 v_t[64 * 232];
    __shared__ float ksum_p[8 * 64];
    __shared__ float ksum[64];

    int bh = blockIdx.x;
    int tid = threadIdx.x;
    int lane = tid & 63, wave = tid >> 6;
    int l15 = lane & 15, l4 = lane >> 4;
    size_t base = (size_t)bh * 12544;

    // zero pad columns [196,232)
    for (int idx = tid; idx < 1152; idx += 512) {
        int c = idx / 18, u = idx - c * 18;
        ((unsigned int*)(k_t + c * 232 + 196))[u] = 0u;
        ((unsigned int*)(v_t + c * 232 + 196))[u] = 0u;
    }
    // load + transpose k, v
    for (int j = tid; j < 3136; j += 512) {
        int e = j * 4, n = e >> 6, c = e & 63;
        half4_t kq = *(const half4_t*)(kh + base + e);
        half4_t vq = *(const half4_t*)(vh + base + e);
        k_t[(c + 0) * 232 + n] = kq[0]; k_t[(c + 1) * 232 + n] = kq[1];
        k_t[(c + 2) * 232 + n] = kq[2]; k_t[(c + 3) * 232 + n] = kq[3];
        v_t[(c + 0) * 232 + n] = vq[0]; v_t[(c + 1) * 232 + n] = vq[1];
        v_t[(c + 2) * 232 + n] = vq[2]; v_t[(c + 3) * 232 + n] = vq[3];
    }
    __syncthreads();

    // kv MFMA: wave -> (ct, dt0), (ct, dt0+1)
    int ct = wave >> 1, dt0 = (wave & 1) * 2;
    f32x4 acc0 = {0.f, 0.f, 0.f, 0.f}, acc1 = {0.f, 0.f, 0.f, 0.f};
    #pragma unroll
    for (int ks = 0; ks < 7; ++ks) {
        half8_t a  = *(const half8_t*)(k_t + (ct * 16 + l15) * 232 + ks * 32 + l4 * 8);
        half8_t b0 = *(const half8_t*)(v_t + (dt0 * 16 + l15) * 232 + ks * 32 + l4 * 8);
        half8_t b1 = *(const half8_t*)(v_t + (dt0 * 16 + 16 + l15) * 232 + ks * 32 + l4 * 8);
        acc0 = MFMA16(a, b0, acc0);
        acc1 = MFMA16(a, b1, acc1);
    }
    {
        half4_t h0, h1;
        #pragma unroll
        for (int r = 0; r < 4; ++r) { h0[r] = (_Float16)acc0[r]; h1[r] = (_Float16)acc1[r]; }
        // store kv transposed: kvg[d][c]
        *(half4_t*)(kvg + (size_t)bh * 4096 + (dt0 * 16 + l15) * 64 + ct * 16 + l4 * 4) = h0;
        *(half4_t*)(kvg + (size_t)bh * 4096 + ((dt0 + 1) * 16 + l15) * 64 + ct * 16 + l4 * 4) = h1;
    }
    // ksum partials
    {
        int n0 = wave * 25;
        int n1 = (n0 + 25 < 196) ? (n0 + 25) : 196;
        float s = 0.f;
        for (int n = n0; n < n1; ++n) s += (float)k_t[lane * 232 + n];
        ksum_p[wave * 64 + lane] = s;
    }
    __syncthreads();
    if (tid < 64) {
        float s = 0.f;
        #pragma unroll
        for (int w = 0; w < 8; ++w) s += ksum_p[w * 64 + tid];
        ksum[tid] = s;
    }
    __syncthreads();
    if (tid < 196) {
        const _Float16* qrow = qh + base + tid * 64;
        float s = 0.f;
        #pragma unroll
        for (int c = 0; c < 64; ++c) s += (float)qrow[c] * ksum[c];
        zg[(size_t)bh * 196 + tid] = 1.0f / (s + 1e-6f);
    }
}

// ---------------- attention part 2: out = z*(q@kv) + dwconv(v), write fused ----------------
#define LDK 72
__global__ __launch_bounds__(512) void attn2_kernel(
    const _Float16* __restrict__ qh, const _Float16* __restrict__ vh,
    const _Float16* __restrict__ kvg, const float* __restrict__ zg,
    const float* __restrict__ dwc_w, const float* __restrict__ dwc_b,
    _Float16* __restrict__ fused) {
    __shared__ _Float16 q_l[208 * LDK];
    __shared__ _Float16 v_n[196 * 64];

    int bh = blockIdx.x;
    int bb = bh / 12, hh = bh - bb * 12;
    int tid = threadIdx.x;
    int lane = tid & 63, wave = tid >> 6;
    int l15 = lane & 15, l4 = lane >> 4;
    size_t base = (size_t)bh * 12544;

    // zero q pad rows [196,208)
    for (int i = tid; i < 432; i += 512) ((unsigned int*)(q_l + 196 * LDK))[i] = 0u;
    for (int j = tid; j < 3136; j += 512) {
        int e = j * 4, n = e >> 6, c = e & 63;
        *(half4_t*)(q_l + n * LDK + c) = *(const half4_t*)(qh + base + e);
        *(half4_t*)(v_n + e) = *(const half4_t*)(vh + base + e);
    }
    __syncthreads();

    for (int t = wave; t < 52; t += 8) {
        int mt = t >> 2, dt = t & 3;
        int d = dt * 16 + l15;
        f32x4 acc = {0.f, 0.f, 0.f, 0.f};
        half8_t a0 = *(const half8_t*)(q_l + (mt * 16 + l15) * LDK + l4 * 8);
        half8_t a1 = *(const half8_t*)(q_l + (mt * 16 + l15) * LDK + 32 + l4 * 8);
        half8_t b0 = *(const half8_t*)(kvg + (size_t)bh * 4096 + d * 64 + l4 * 8);
        half8_t b1 = *(const half8_t*)(kvg + (size_t)bh * 4096 + d * 64 + 32 + l4 * 8);
        acc = MFMA16(a0, b0, acc);
        acc = MFMA16(a1, b1, acc);

        float bd = dwc_b[d];
        float wc[25];
        #pragma unroll
        for (int j2 = 0; j2 < 25; ++j2) wc[j2] = dwc_w[d * 25 + j2];

        #pragma unroll
        for (int r = 0; r < 4; ++r) {
            int i = mt * 16 + l4 * 4 + r;
            if (i < 196) {
                int y = i / 14, x2 = i - y * 14;
                float cacc = bd;
                #pragma unroll
                for (int ky = 0; ky < 5; ++ky) {
                    int yy = y + ky - 2;
                    bool oky = (unsigned)yy < 14u;
                    #pragma unroll
                    for (int kx = 0; kx < 5; ++kx) {
                        int xx = x2 + kx - 2;
                        if (oky && (unsigned)xx < 14u)
                            cacc += (float)v_n[(yy * 14 + xx) * 64 + d] * wc[ky * 5 + kx];
                    }
                }
                float res = acc[r] * zg[(size_t)bh * 196 + i] + cacc;
                fused[((size_t)bb * 196 + i) * 768 + hh * 64 + d] = (_Float16)res;
            }
        }
    }
}

// ---------------- launcher ----------------

extern "C" void kernel_launch(void* const* d_in, const int* in_sizes, int n_in,
                              void* d_out, int out_size, void* d_ws, size_t ws_size,
                              hipStream_t stream) {
    const float* x       = (const float*)d_in[0];
    const float* w_qkv   = (const float*)d_in[1];
    const float* pos_enc = (const float*)d_in[2];
    const float* dwc_w   = (const float*)d_in[3];
    const float* dwc_b   = (const float*)d_in[4];
    const float* w_proj  = (const float*)d_in[5];
    const float* b_proj  = (const float*)d_in[6];

    const size_t NEEDED = 340574208;
    if (ws_size < NEEDED) return;  // insufficient scratch; bail (output stays poisoned)

    char* ws = (char*)d_ws;
    _Float16* xh     = (_Float16*)(ws + 0);          // 77,070,336 B (also 'fused' later)
    _Float16* fused  = xh;
    _Float16* wqkvT  = (_Float16*)(ws + 77070336);   // 3,538,944
    _Float16* wprojT = (_Float16*)(ws + 80609280);   // 1,179,648
    _Float16* qh     = (_Float16*)(ws + 81788928);   // 77,070,336
    _Float16* kh     = (_Float16*)(ws + 158859264);  // 77,070,336
    _Float16* vh     = (_Float16*)(ws + 235929600);  // 77,070,336
    _Float16* kvg    = (_Float16*)(ws + 312999936);  // 25,165,824
    float*    zg     = (float*)(ws + 338165760);     // 2,408,448

    cvt_f2h_kernel<<<4096, 256, 0, stream>>>(x, xh, 9633792);
    transpose768_kernel<<<(2304 * 768 + 255) / 256, 256, 0, stream>>>(w_qkv, wqkvT, 2304);
    transpose768_kernel<<<(768 * 768 + 255) / 256, 256, 0, stream>>>(w_proj, wprojT, 768);
    gemm_qkv_kernel<<<196 * 9, 512, 0, stream>>>(xh, wqkvT, pos_enc, qh, kh, vh);
    attn1_kernel<<<3072, 512, 0, stream>>>(qh, kh, vh, kvg, zg);
    attn2_kernel<<<3072, 512, 0, stream>>>(qh, vh, kvg, zg, dwc_w, dwc_b, fused);
    gemm_proj_kernel<<<196 * 3, 512, 0, stream>>>(fused, wprojT, b_proj, (float*)d_out);
}

// Round 4
// 819.836 us; speedup vs baseline: 1.0430x; 1.0193x over previous
//
#include <hip/hip_runtime.h>

typedef _Float16 half8_t __attribute__((ext_vector_type(8)));
typedef _Float16 half4_t __attribute__((ext_vector_type(4)));
typedef float f32x4 __attribute__((ext_vector_type(4)));

#define MFMA16(a, b, c) __builtin_amdgcn_mfma_f32_16x16x32_f16((a), (b), (c), 0, 0, 0)

typedef const unsigned int __attribute__((address_space(1)))* gas_ptr;
typedef unsigned int __attribute__((address_space(3)))* las_ptr;

__device__ __forceinline__ void gload16(const void* g, void* l) {
    __builtin_amdgcn_global_load_lds((gas_ptr)g, (las_ptr)l, 16, 0, 0);
}

// m204 bijective XCD swizzle: contiguous wgid chunk per XCD (works for nwg % 8 != 0)
__device__ __forceinline__ int xcd_swizzle(int bid, int nwg) {
    int xcd = bid & 7, i = bid >> 3;
    int q = nwg >> 3, r = nwg & 7;
    return (xcd < r ? xcd * (q + 1) : r * (q + 1) + (xcd - r) * q) + i;
}

// ---------------- convert / transpose ----------------

__global__ void cvt_f2h_kernel(const float* __restrict__ in, _Float16* __restrict__ out, int n4) {
    int stride = gridDim.x * blockDim.x;
    for (int i = blockIdx.x * blockDim.x + threadIdx.x; i < n4; i += stride) {
        f32x4 v = *(const f32x4*)(in + (size_t)4 * i);
        half4_t h;
        h[0] = (_Float16)v[0]; h[1] = (_Float16)v[1];
        h[2] = (_Float16)v[2]; h[3] = (_Float16)v[3];
        *(half4_t*)(out + (size_t)4 * i) = h;
    }
}

// out[j][k] = in[k][j], K fixed at 768
__global__ void transpose768_kernel(const float* __restrict__ in, _Float16* __restrict__ out, int ncols) {
    int idx = blockIdx.x * 256 + threadIdx.x;
    int total = ncols * 768;
    if (idx < total) {
        int j = idx / 768;
        int k = idx - j * 768;
        out[idx] = (_Float16)in[(size_t)k * ncols + j];
    }
}

// ---------------- GEMM core: 256x256 tile, BK=64, 8 waves (2Mx4N), dbuf gload_lds ----------------
// A: [M][768] f16 (K contiguous); Bt: [Nout][768] f16 (K contiguous)
// LDS per operand per buffer: linear [256][64] f16 (128 B rows), 32 KiB.
// XOR swizzle (both-sides, rule #21): LDS[r][slot s] holds G[r][s ^ (r&7)]
//   - staged via pre-swizzled global source (dest stays linear for gload_lds)
//   - frag reads XOR the slot with row&7 -> 8 lanes span all 32 banks (2-way = free)

__device__ __forceinline__ void run_gemm256(const _Float16* __restrict__ A,
                                            const _Float16* __restrict__ Bt,
                                            int mbase, int nbase,
                                            _Float16* As, _Float16* Bs,  // [2][16384] each
                                            f32x4 (&acc)[8][4]) {
    const int tid = threadIdx.x;
    const int lane = tid & 63;
    const int wave = tid >> 6;
    const int wr = wave >> 2;        // 0..1  (M half)
    const int wc = wave & 3;         // 0..3  (N quarter)
    const int l15 = lane & 15;
    const int l4 = lane >> 4;
    const int rl = lane >> 3;                      // staging row-in-chunk 0..7
    const int cs = ((lane & 7) ^ rl) * 8;          // pre-swizzled source col (elements)
    const int sx = l15 & 7;                        // read-side swizzle key

    #pragma unroll
    for (int mi = 0; mi < 8; ++mi)
        #pragma unroll
        for (int ni = 0; ni < 4; ++ni)
            acc[mi][ni] = (f32x4){0.f, 0.f, 0.f, 0.f};

    const _Float16* Abase = A + (size_t)mbase * 768;
    const _Float16* Bbase = Bt + (size_t)nbase * 768;

    // stage K-tile kt into buffer buf: 256x64 f16 per operand = 4 gload16/thread each
    #define STAGE256(buf, kof)                                                          \
        {                                                                               \
            _Float16* Ad = As + (buf) * 16384;                                          \
            _Float16* Bd = Bs + (buf) * 16384;                                          \
            _Pragma("unroll")                                                           \
            for (int i = 0; i < 4; ++i) {                                               \
                int row = i * 64 + wave * 8 + rl;                                       \
                gload16(Abase + (size_t)row * 768 + (kof) + cs,                         \
                        (char*)Ad + i * 8192 + wave * 1024);                            \
                gload16(Bbase + (size_t)row * 768 + (kof) + cs,                         \
                        (char*)Bd + i * 8192 + wave * 1024);                            \
            }                                                                           \
        }

    STAGE256(0, 0)
    __syncthreads();

    int cur = 0;
    for (int kt = 0; kt < 12; ++kt) {
        if (kt + 1 < 12) STAGE256(cur ^ 1, (kt + 1) * 64)

        const _Float16* Ac = As + cur * 16384;
        const _Float16* Bc = Bs + cur * 16384;
        #pragma unroll
        for (int ks = 0; ks < 2; ++ks) {
            half8_t b[4];
            #pragma unroll
            for (int ni = 0; ni < 4; ++ni)
                b[ni] = *(const half8_t*)(Bc + (wc * 64 + ni * 16 + l15) * 64 +
                                          (((ks * 4 + l4) ^ sx) << 3));
            #pragma unroll
            for (int mi = 0; mi < 8; ++mi) {
                half8_t a = *(const half8_t*)(Ac + (wr * 128 + mi * 16 + l15) * 64 +
                                              (((ks * 4 + l4) ^ sx) << 3));
                #pragma unroll
                for (int ni = 0; ni < 4; ++ni)
                    acc[mi][ni] = MFMA16(a, b[ni], acc[mi][ni]);
            }
        }
        __syncthreads();
        cur ^= 1;
    }
    #undef STAGE256
}

// GEMM1: qkv = x @ w_qkv, epilogue: +pos_enc (k), relu (q,k), scatter to head layout
__global__ __launch_bounds__(512, 2) void gemm_qkv_kernel(
    const _Float16* __restrict__ xh, const _Float16* __restrict__ wqkvT,
    const float* __restrict__ pos_enc,
    _Float16* __restrict__ qh, _Float16* __restrict__ kh, _Float16* __restrict__ vh) {
    __shared__ _Float16 As[2][16384];
    __shared__ _Float16 Bs[2][16384];
    // XCD-grouped: 9 consecutive wgids (one mtile's ntiles) land on one XCD -> A panel L2-shared
    int wgid = xcd_swizzle(blockIdx.x, 196 * 9);
    int mtile = wgid / 9, ntile = wgid - mtile * 9;
    f32x4 acc[8][4];
    run_gemm256(xh, wqkvT, mtile * 256, ntile * 256, &As[0][0], &Bs[0][0], acc);

    const int tid = threadIdx.x;
    const int lane = tid & 63;
    const int wave = tid >> 6;
    const int wr = wave >> 2;
    const int wc = wave & 3;
    const int l15 = lane & 15;
    const int l4 = lane >> 4;

    // 768 = 3*256: all 256 columns of this block live in one q/k/v segment
    const int s = ntile / 3;
    const int cb = (ntile - s * 3) * 256 + wc * 64;
    _Float16* dst = (s == 0) ? qh : ((s == 1) ? kh : vh);

    #pragma unroll
    for (int mi = 0; mi < 8; ++mi) {
        #pragma unroll
        for (int ni = 0; ni < 4; ++ni) {
            int c = cb + ni * 16 + l15;
            int h = c >> 6, d = c & 63;
            #pragma unroll
            for (int r = 0; r < 4; ++r) {
                int gr = mtile * 256 + wr * 128 + mi * 16 + l4 * 4 + r;
                int b = gr / 196;
                int n = gr - b * 196;
                float v = acc[mi][ni][r];
                if (s == 1) v += pos_enc[n * 768 + c];
                if (s < 2) v = fmaxf(v, 0.f);
                dst[((size_t)(b * 12 + h) * 196 + n) * 64 + d] = (_Float16)v;
            }
        }
    }
}

// GEMM2: out = fused @ w_proj + b_proj (f32 out)
__global__ __launch_bounds__(512, 2) void gemm_proj_kernel(
    const _Float16* __restrict__ fused, const _Float16* __restrict__ wprojT,
    const float* __restrict__ b_proj, float* __restrict__ out) {
    __shared__ _Float16 As[2][16384];
    __shared__ _Float16 Bs[2][16384];
    int wgid = xcd_swizzle(blockIdx.x, 196 * 3);
    int mtile = wgid / 3, ntile = wgid - mtile * 3;
    f32x4 acc[8][4];
    run_gemm256(fused, wprojT, mtile * 256, ntile * 256, &As[0][0], &Bs[0][0], acc);

    const int tid = threadIdx.x;
    const int lane = tid & 63;
    const int wave = tid >> 6;
    const int wr = wave >> 2;
    const int wc = wave & 3;
    const int l15 = lane & 15;
    const int l4 = lane >> 4;

    #pragma unroll
    for (int mi = 0; mi < 8; ++mi) {
        #pragma unroll
        for (int ni = 0; ni < 4; ++ni) {
            int gc = ntile * 256 + wc * 64 + ni * 16 + l15;
            float bp = b_proj[gc];
            #pragma unroll
            for (int r = 0; r < 4; ++r) {
                int gr = mtile * 256 + wr * 128 + mi * 16 + l4 * 4 + r;
                out[(size_t)gr * 768 + gc] = acc[mi][ni][r] + bp;
            }
        }
    }
}

// ---------------- attention part 1: kv = k^T v (64x64), ksum, z ----------------
__global__ __launch_bounds__(512) void attn1_kernel(
    const _Float16* __restrict__ qh, const _Float16* __restrict__ kh,
    const _Float16* __restrict__ vh, _Float16* __restrict__ kvg, float* __restrict__ zg) {
    __shared__ _Float16 k_t[64 * 232];
    __shared__ _Float16 v_t[64 * 232];
    __shared__ float ksum_p[8 * 64];
    __shared__ float ksum[64];

    int bh = blockIdx.x;
    int tid = threadIdx.x;
    int lane = tid & 63, wave = tid >> 6;
    int l15 = lane & 15, l4 = lane >> 4;
    size_t base = (size_t)bh * 12544;

    // zero pad columns [196,232)
    for (int idx = tid; idx < 1152; idx += 512) {
        int c = idx / 18, u = idx - c * 18;
        ((unsigned int*)(k_t + c * 232 + 196))[u] = 0u;
        ((unsigned int*)(v_t + c * 232 + 196))[u] = 0u;
    }
    // load + transpose k, v
    for (int j = tid; j < 3136; j += 512) {
        int e = j * 4, n = e >> 6, c = e & 63;
        half4_t kq = *(const half4_t*)(kh + base + e);
        half4_t vq = *(const half4_t*)(vh + base + e);
        k_t[(c + 0) * 232 + n] = kq[0]; k_t[(c + 1) * 232 + n] = kq[1];
        k_t[(c + 2) * 232 + n] = kq[2]; k_t[(c + 3) * 232 + n] = kq[3];
        v_t[(c + 0) * 232 + n] = vq[0]; v_t[(c + 1) * 232 + n] = vq[1];
        v_t[(c + 2) * 232 + n] = vq[2]; v_t[(c + 3) * 232 + n] = vq[3];
    }
    __syncthreads();

    // kv MFMA: wave -> (ct, dt0), (ct, dt0+1)
    int ct = wave >> 1, dt0 = (wave & 1) * 2;
    f32x4 acc0 = {0.f, 0.f, 0.f, 0.f}, acc1 = {0.f, 0.f, 0.f, 0.f};
    #pragma unroll
    for (int ks = 0; ks < 7; ++ks) {
        half8_t a  = *(const half8_t*)(k_t + (ct * 16 + l15) * 232 + ks * 32 + l4 * 8);
        half8_t b0 = *(const half8_t*)(v_t + (dt0 * 16 + l15) * 232 + ks * 32 + l4 * 8);
        half8_t b1 = *(const half8_t*)(v_t + (dt0 * 16 + 16 + l15) * 232 + ks * 32 + l4 * 8);
        acc0 = MFMA16(a, b0, acc0);
        acc1 = MFMA16(a, b1, acc1);
    }
    {
        half4_t h0, h1;
        #pragma unroll
        for (int r = 0; r < 4; ++r) { h0[r] = (_Float16)acc0[r]; h1[r] = (_Float16)acc1[r]; }
        // store kv transposed: kvg[d][c]
        *(half4_t*)(kvg + (size_t)bh * 4096 + (dt0 * 16 + l15) * 64 + ct * 16 + l4 * 4) = h0;
        *(half4_t*)(kvg + (size_t)bh * 4096 + ((dt0 + 1) * 16 + l15) * 64 + ct * 16 + l4 * 4) = h1;
    }
    // ksum partials
    {
        int n0 = wave * 25;
        int n1 = (n0 + 25 < 196) ? (n0 + 25) : 196;
        float s = 0.f;
        for (int n = n0; n < n1; ++n) s += (float)k_t[lane * 232 + n];
        ksum_p[wave * 64 + lane] = s;
    }
    __syncthreads();
    if (tid < 64) {
        float s = 0.f;
        #pragma unroll
        for (int w = 0; w < 8; ++w) s += ksum_p[w * 64 + tid];
        ksum[tid] = s;
    }
    __syncthreads();
    if (tid < 196) {
        const _Float16* qrow = qh + base + tid * 64;
        float s = 0.f;
        #pragma unroll
        for (int c = 0; c < 64; ++c) s += (float)qrow[c] * ksum[c];
        zg[(size_t)bh * 196 + tid] = 1.0f / (s + 1e-6f);
    }
}

// ---------------- attention part 2: out = z*(q@kv) + dwconv(v), write fused ----------------
#define LDK 72
__global__ __launch_bounds__(512) void attn2_kernel(
    const _Float16* __restrict__ qh, const _Float16* __restrict__ vh,
    const _Float16* __restrict__ kvg, const float* __restrict__ zg,
    const float* __restrict__ dwc_w, const float* __restrict__ dwc_b,
    _Float16* __restrict__ fused) {
    __shared__ _Float16 q_l[208 * LDK];
    __shared__ _Float16 v_n[196 * 64];

    int bh = blockIdx.x;
    int bb = bh / 12, hh = bh - bb * 12;
    int tid = threadIdx.x;
    int lane = tid & 63, wave = tid >> 6;
    int l15 = lane & 15, l4 = lane >> 4;
    size_t base = (size_t)bh * 12544;

    // zero q pad rows [196,208)
    for (int i = tid; i < 432; i += 512) ((unsigned int*)(q_l + 196 * LDK))[i] = 0u;
    for (int j = tid; j < 3136; j += 512) {
        int e = j * 4, n = e >> 6, c = e & 63;
        *(half4_t*)(q_l + n * LDK + c) = *(const half4_t*)(qh + base + e);
        *(half4_t*)(v_n + e) = *(const half4_t*)(vh + base + e);
    }
    __syncthreads();

    for (int t = wave; t < 52; t += 8) {
        int mt = t >> 2, dt = t & 3;
        int d = dt * 16 + l15;
        f32x4 acc = {0.f, 0.f, 0.f, 0.f};
        half8_t a0 = *(const half8_t*)(q_l + (mt * 16 + l15) * LDK + l4 * 8);
        half8_t a1 = *(const half8_t*)(q_l + (mt * 16 + l15) * LDK + 32 + l4 * 8);
        half8_t b0 = *(const half8_t*)(kvg + (size_t)bh * 4096 + d * 64 + l4 * 8);
        half8_t b1 = *(const half8_t*)(kvg + (size_t)bh * 4096 + d * 64 + 32 + l4 * 8);
        acc = MFMA16(a0, b0, acc);
        acc = MFMA16(a1, b1, acc);

        float bd = dwc_b[d];
        float wc[25];
        #pragma unroll
        for (int j2 = 0; j2 < 25; ++j2) wc[j2] = dwc_w[d * 25 + j2];

        #pragma unroll
        for (int r = 0; r < 4; ++r) {
            int i = mt * 16 + l4 * 4 + r;
            if (i < 196) {
                int y = i / 14, x2 = i - y * 14;
                float cacc = bd;
                #pragma unroll
                for (int ky = 0; ky < 5; ++ky) {
                    int yy = y + ky - 2;
                    bool oky = (unsigned)yy < 14u;
                    #pragma unroll
                    for (int kx = 0; kx < 5; ++kx) {
                        int xx = x2 + kx - 2;
                        if (oky && (unsigned)xx < 14u)
                            cacc += (float)v_n[(yy * 14 + xx) * 64 + d] * wc[ky * 5 + kx];
                    }
                }
                float res = acc[r] * zg[(size_t)bh * 196 + i] + cacc;
                fused[((size_t)bb * 196 + i) * 768 + hh * 64 + d] = (_Float16)res;
            }
        }
    }
}

// ---------------- launcher ----------------

extern "C" void kernel_launch(void* const* d_in, const int* in_sizes, int n_in,
                              void* d_out, int out_size, void* d_ws, size_t ws_size,
                              hipStream_t stream) {
    const float* x       = (const float*)d_in[0];
    const float* w_qkv   = (const float*)d_in[1];
    const float* pos_enc = (const float*)d_in[2];
    const float* dwc_w   = (const float*)d_in[3];
    const float* dwc_b   = (const float*)d_in[4];
    const float* w_proj  = (const float*)d_in[5];
    const float* b_proj  = (const float*)d_in[6];

    const size_t NEEDED = 340574208;
    if (ws_size < NEEDED) return;  // insufficient scratch; bail (output stays poisoned)

    char* ws = (char*)d_ws;
    _Float16* xh     = (_Float16*)(ws + 0);          // 77,070,336 B (also 'fused' later)
    _Float16* fused  = xh;
    _Float16* wqkvT  = (_Float16*)(ws + 77070336);   // 3,538,944
    _Float16* wprojT = (_Float16*)(ws + 80609280);   // 1,179,648
    _Float16* qh     = (_Float16*)(ws + 81788928);   // 77,070,336
    _Float16* kh     = (_Float16*)(ws + 158859264);  // 77,070,336
    _Float16* vh     = (_Float16*)(ws + 235929600);  // 77,070,336
    _Float16* kvg    = (_Float16*)(ws + 312999936);  // 25,165,824
    float*    zg     = (float*)(ws + 338165760);     // 2,408,448

    cvt_f2h_kernel<<<4096, 256, 0, stream>>>(x, xh, 9633792);
    transpose768_kernel<<<(2304 * 768 + 255) / 256, 256, 0, stream>>>(w_qkv, wqkvT, 2304);
    transpose768_kernel<<<(768 * 768 + 255) / 256, 256, 0, stream>>>(w_proj, wprojT, 768);
    gemm_qkv_kernel<<<196 * 9, 512, 0, stream>>>(xh, wqkvT, pos_enc, qh, kh, vh);
    attn1_kernel<<<3072, 512, 0, stream>>>(qh, kh, vh, kvg, zg);
    attn2_kernel<<<3072, 512, 0, stream>>>(qh, vh, kvg, zg, dwc_w, dwc_b, fused);
    gemm_proj_kernel<<<196 * 3, 512, 0, stream>>>(fused, wprojT, b_proj, (float*)d_out);
}

// Round 5
// 746.171 us; speedup vs baseline: 1.1459x; 1.0987x over previous
//
#include <hip/hip_runtime.h>

typedef _Float16 half8_t __attribute__((ext_vector_type(8)));
typedef _Float16 half4_t __attribute__((ext_vector_type(4)));
typedef float f32x4 __attribute__((ext_vector_type(4)));

#define MFMA16(a, b, c) __builtin_amdgcn_mfma_f32_16x16x32_f16((a), (b), (c), 0, 0, 0)

typedef const unsigned int __attribute__((address_space(1)))* gas_ptr;
typedef unsigned int __attribute__((address_space(3)))* las_ptr;

__device__ __forceinline__ void gload16(const void* g, void* l) {
    __builtin_amdgcn_global_load_lds((gas_ptr)g, (las_ptr)l, 16, 0, 0);
}

// m204 bijective XCD swizzle: contiguous wgid chunk per XCD (works for nwg % 8 != 0)
__device__ __forceinline__ int xcd_swizzle(int bid, int nwg) {
    int xcd = bid & 7, i = bid >> 3;
    int q = nwg >> 3, r = nwg & 7;
    return (xcd < r ? xcd * (q + 1) : r * (q + 1) + (xcd - r) * q) + i;
}

// ---------------- convert / transpose ----------------

__global__ void cvt_f2h_kernel(const float* __restrict__ in, _Float16* __restrict__ out, int n4) {
    int stride = gridDim.x * blockDim.x;
    for (int i = blockIdx.x * blockDim.x + threadIdx.x; i < n4; i += stride) {
        f32x4 v = *(const f32x4*)(in + (size_t)4 * i);
        half4_t h;
        h[0] = (_Float16)v[0]; h[1] = (_Float16)v[1];
        h[2] = (_Float16)v[2]; h[3] = (_Float16)v[3];
        *(half4_t*)(out + (size_t)4 * i) = h;
    }
}

// out[j][k] = in[k][j], K fixed at 768
__global__ void transpose768_kernel(const float* __restrict__ in, _Float16* __restrict__ out, int ncols) {
    int idx = blockIdx.x * 256 + threadIdx.x;
    int total = ncols * 768;
    if (idx < total) {
        int j = idx / 768;
        int k = idx - j * 768;
        out[idx] = (_Float16)in[(size_t)k * ncols + j];
    }
}

// ---------------- GEMM core: 256x256 tile, BK=64, 8 waves, counted-vmcnt phase pipeline ----
// A: [M][768] f16 (K contiguous); Bt: [Nout][768] f16 (K contiguous)
// Staging chunk = one operand, 256 rows x 32 K-cols, 16 KiB, 2 gload16/thread.
// LDS slots: [parity][khalf][op] x 16 KiB = 128 KiB. Chunk layout [256 rows][32 k] with
// k-slot XOR swizzle: LDS row r, 16B-slot s holds global k-group (s ^ (r&3)) — staged via
// pre-swizzled global source (linear LDS dest for gload_lds, rule #21), read with same XOR.
// 24 phases; phase n: vmcnt(8) -> barrier -> ds_read frags -> issue phase n+3 chunks ->
// setprio(1) 32 MFMA setprio(0). Tail waits 8 -> 4 -> 0; no vmcnt(0) in steady state (T4).

#define SLOTP(par, hf, op) (lds + (((par) * 2 + (hf)) * 2 + (op)) * 8192)

#define STAGEC(par, hf, gk)                                                       \
    {                                                                             \
        _Float16* Ad = SLOTP(par, hf, 0);                                         \
        _Float16* Bd = SLOTP(par, hf, 1);                                         \
        gload16(Arow + (gk),          Ad + wave * 512);                           \
        gload16(Arow + (gk) + 98304,  Ad + 4096 + wave * 512);                    \
        gload16(Brow + (gk),          Bd + wave * 512);                           \
        gload16(Brow + (gk) + 98304,  Bd + 4096 + wave * 512);                    \
    }

#define PHASE(par, hf, VM, DOSTG, spar, shf, sgk)                                 \
    {                                                                             \
        asm volatile("s_waitcnt vmcnt(%0)" :: "i"(VM) : "memory");                \
        __builtin_amdgcn_s_barrier();                                             \
        const _Float16* Ac = SLOTP(par, hf, 0);                                   \
        const _Float16* Bc = SLOTP(par, hf, 1);                                   \
        half8_t bfr[4], afr[8];                                                   \
        _Pragma("unroll")                                                         \
        for (int ni = 0; ni < 4; ++ni)                                            \
            bfr[ni] = *(const half8_t*)(Bc + (wc * 64 + ni * 16 + l15) * 32 +     \
                                        ((l4 ^ fx) << 3));                        \
        _Pragma("unroll")                                                         \
        for (int mi = 0; mi < 8; ++mi)                                            \
            afr[mi] = *(const half8_t*)(Ac + (wr * 128 + mi * 16 + l15) * 32 +    \
                                        ((l4 ^ fx) << 3));                        \
        if (DOSTG) STAGEC(spar, shf, sgk)                                         \
        __builtin_amdgcn_s_setprio(1);                                            \
        _Pragma("unroll")                                                         \
        for (int mi = 0; mi < 8; ++mi)                                            \
            _Pragma("unroll")                                                     \
            for (int ni = 0; ni < 4; ++ni)                                        \
                acc[mi][ni] = MFMA16(afr[mi], bfr[ni], acc[mi][ni]);              \
        __builtin_amdgcn_s_setprio(0);                                            \
    }

__device__ __forceinline__ void run_gemm256(const _Float16* __restrict__ A,
                                            const _Float16* __restrict__ Bt,
                                            int mbase, int nbase,
                                            _Float16* lds,          // [2][2][2][8192]
                                            f32x4 (&acc)[8][4]) {
    const int tid = threadIdx.x;
    const int lane = tid & 63;
    const int wave = tid >> 6;
    const int wr = wave >> 2;        // 0..1  (M half)
    const int wc = wave & 3;         // 0..3  (N quarter)
    const int l15 = lane & 15;
    const int l4 = lane >> 4;
    const int rsl = lane >> 2;                 // staging row-in-sweep-wave 0..15
    const int ksw = ((lane & 3) ^ (rsl & 3)) << 3;  // pre-swizzled k-elem offset (rule #21)
    const int fx = l15 & 3;                    // read-side swizzle key

    #pragma unroll
    for (int mi = 0; mi < 8; ++mi)
        #pragma unroll
        for (int ni = 0; ni < 4; ++ni)
            acc[mi][ni] = (f32x4){0.f, 0.f, 0.f, 0.f};

    // per-thread staging source base (sweep 0 row; sweep 1 adds 128*768 = 98304)
    const _Float16* Arow = A + (size_t)(mbase + wave * 16 + rsl) * 768 + ksw;
    const _Float16* Brow = Bt + (size_t)(nbase + wave * 16 + rsl) * 768 + ksw;

    // prologue: stage chunks for phases 0,1,2 = (t0,h0), (t0,h1), (t1,h0)
    STAGEC(0, 0, 0)
    STAGEC(0, 1, 32)
    STAGEC(1, 0, 64)

    // phases 0..21 (K-tiles 0..10): steady vmcnt(8)
    for (int kt = 0; kt < 11; ++kt) {
        const int par = kt & 1;
        // phase 2kt   : stage (kt+1, half1)
        PHASE(par, 0, 8, true, (kt + 1) & 1, 1, (kt + 1) * 64 + 32)
        // phase 2kt+1 : stage (kt+2, half0) — skip at kt=10 (no tile 12)
        if (kt < 10) {
            PHASE(par, 1, 8, true, (kt + 2) & 1, 0, (kt + 2) * 64)
        } else {
            PHASE(par, 1, 8, false, 0, 0, 0)
        }
    }
    // K-tile 11: tail drain 4 -> 0
    PHASE(1, 0, 4, false, 0, 0, 0)
    PHASE(1, 1, 0, false, 0, 0, 0)
}

// GEMM1: qkv = x @ w_qkv, epilogue: +pos_enc (k), relu (q,k), scatter to head layout
__global__ __launch_bounds__(512, 2) void gemm_qkv_kernel(
    const _Float16* __restrict__ xh, const _Float16* __restrict__ wqkvT,
    const float* __restrict__ pos_enc,
    _Float16* __restrict__ qh, _Float16* __restrict__ kh, _Float16* __restrict__ vh) {
    __shared__ _Float16 lds[2 * 2 * 2 * 8192];
    // XCD-grouped: 9 consecutive wgids (one mtile's ntiles) land on one XCD -> A panel L2-shared
    int wgid = xcd_swizzle(blockIdx.x, 196 * 9);
    int mtile = wgid / 9, ntile = wgid - mtile * 9;
    f32x4 acc[8][4];
    run_gemm256(xh, wqkvT, mtile * 256, ntile * 256, lds, acc);

    const int tid = threadIdx.x;
    const int lane = tid & 63;
    const int wave = tid >> 6;
    const int wr = wave >> 2;
    const int wc = wave & 3;
    const int l15 = lane & 15;
    const int l4 = lane >> 4;

    // 768 = 3*256: all 256 columns of this block live in one q/k/v segment
    const int s = ntile / 3;
    const int cb = (ntile - s * 3) * 256 + wc * 64;
    _Float16* dst = (s == 0) ? qh : ((s == 1) ? kh : vh);

    #pragma unroll
    for (int mi = 0; mi < 8; ++mi) {
        #pragma unroll
        for (int ni = 0; ni < 4; ++ni) {
            int c = cb + ni * 16 + l15;
            int h = c >> 6, d = c & 63;
            #pragma unroll
            for (int r = 0; r < 4; ++r) {
                int gr = mtile * 256 + wr * 128 + mi * 16 + l4 * 4 + r;
                int b = gr / 196;
                int n = gr - b * 196;
                float v = acc[mi][ni][r];
                if (s == 1) v += pos_enc[n * 768 + c];
                if (s < 2) v = fmaxf(v, 0.f);
                dst[((size_t)(b * 12 + h) * 196 + n) * 64 + d] = (_Float16)v;
            }
        }
    }
}

// GEMM2: out = fused @ w_proj + b_proj (f32 out)
__global__ __launch_bounds__(512, 2) void gemm_proj_kernel(
    const _Float16* __restrict__ fused, const _Float16* __restrict__ wprojT,
    const float* __restrict__ b_proj, float* __restrict__ out) {
    __shared__ _Float16 lds[2 * 2 * 2 * 8192];
    int wgid = xcd_swizzle(blockIdx.x, 196 * 3);
    int mtile = wgid / 3, ntile = wgid - mtile * 3;
    f32x4 acc[8][4];
    run_gemm256(fused, wprojT, mtile * 256, ntile * 256, lds, acc);

    const int tid = threadIdx.x;
    const int lane = tid & 63;
    const int wave = tid >> 6;
    const int wr = wave >> 2;
    const int wc = wave & 3;
    const int l15 = lane & 15;
    const int l4 = lane >> 4;

    #pragma unroll
    for (int mi = 0; mi < 8; ++mi) {
        #pragma unroll
        for (int ni = 0; ni < 4; ++ni) {
            int gc = ntile * 256 + wc * 64 + ni * 16 + l15;
            float bp = b_proj[gc];
            #pragma unroll
            for (int r = 0; r < 4; ++r) {
                int gr = mtile * 256 + wr * 128 + mi * 16 + l4 * 4 + r;
                out[(size_t)gr * 768 + gc] = acc[mi][ni][r] + bp;
            }
        }
    }
}

// ---------------- attention part 1: kv = k^T v (64x64), ksum, z ----------------
__global__ __launch_bounds__(512) void attn1_kernel(
    const _Float16* __restrict__ qh, const _Float16* __restrict__ kh,
    const _Float16* __restrict__ vh, _Float16* __restrict__ kvg, float* __restrict__ zg) {
    __shared__ _Float16 k_t[64 * 232];
    __shared__ _Float16 v_t[64 * 232];
    __shared__ float ksum_p[8 * 64];
    __shared__ float ksum[64];

    int bh = blockIdx.x;
    int tid = threadIdx.x;
    int lane = tid & 63, wave = tid >> 6;
    int l15 = lane & 15, l4 = lane >> 4;
    size_t base = (size_t)bh * 12544;

    // zero pad columns [196,232)
    for (int idx = tid; idx < 1152; idx += 512) {
        int c = idx / 18, u = idx - c * 18;
        ((unsigned int*)(k_t + c * 232 + 196))[u] = 0u;
        ((unsigned int*)(v_t + c * 232 + 196))[u] = 0u;
    }
    // load + transpose k, v
    for (int j = tid; j < 3136; j += 512) {
        int e = j * 4, n = e >> 6, c = e & 63;
        half4_t kq = *(const half4_t*)(kh + base + e);
        half4_t vq = *(const half4_t*)(vh + base + e);
        k_t[(c + 0) * 232 + n] = kq[0]; k_t[(c + 1) * 232 + n] = kq[1];
        k_t[(c + 2) * 232 + n] = kq[2]; k_t[(c + 3) * 232 + n] = kq[3];
        v_t[(c + 0) * 232 + n] = vq[0]; v_t[(c + 1) * 232 + n] = vq[1];
        v_t[(c + 2) * 232 + n] = vq[2]; v_t[(c + 3) * 232 + n] = vq[3];
    }
    __syncthreads();

    // kv MFMA: wave -> (ct, dt0), (ct, dt0+1)
    int ct = wave >> 1, dt0 = (wave & 1) * 2;
    f32x4 acc0 = {0.f, 0.f, 0.f, 0.f}, acc1 = {0.f, 0.f, 0.f, 0.f};
    #pragma unroll
    for (int ks = 0; ks < 7; ++ks) {
        half8_t a  = *(const half8_t*)(k_t + (ct * 16 + l15) * 232 + ks * 32 + l4 * 8);
        half8_t b0 = *(const half8_t*)(v_t + (dt0 * 16 + l15) * 232 + ks * 32 + l4 * 8);
        half8_t b1 = *(const half8_t*)(v_t + (dt0 * 16 + 16 + l15) * 232 + ks * 32 + l4 * 8);
        acc0 = MFMA16(a, b0, acc0);
        acc1 = MFMA16(a, b1, acc1);
    }
    {
        half4_t h0, h1;
        #pragma unroll
        for (int r = 0; r < 4; ++r) { h0[r] = (_Float16)acc0[r]; h1[r] = (_Float16)acc1[r]; }
        // store kv transposed: kvg[d][c]
        *(half4_t*)(kvg + (size_t)bh * 4096 + (dt0 * 16 + l15) * 64 + ct * 16 + l4 * 4) = h0;
        *(half4_t*)(kvg + (size_t)bh * 4096 + ((dt0 + 1) * 16 + l15) * 64 + ct * 16 + l4 * 4) = h1;
    }
    // ksum partials
    {
        int n0 = wave * 25;
        int n1 = (n0 + 25 < 196) ? (n0 + 25) : 196;
        float s = 0.f;
        for (int n = n0; n < n1; ++n) s += (float)k_t[lane * 232 + n];
        ksum_p[wave * 64 + lane] = s;
    }
    __syncthreads();
    if (tid < 64) {
        float s = 0.f;
        #pragma unroll
        for (int w = 0; w < 8; ++w) s += ksum_p[w * 64 + tid];
        ksum[tid] = s;
    }
    __syncthreads();
    if (tid < 196) {
        const _Float16* qrow = qh + base + tid * 64;
        float s = 0.f;
        #pragma unroll
        for (int c = 0; c < 64; ++c) s += (float)qrow[c] * ksum[c];
        zg[(size_t)bh * 196 + tid] = 1.0f / (s + 1e-6f);
    }
}

// ---------------- attention part 2: out = z*(q@kv) + dwconv(v), write fused ----------------
#define LDK 72
__global__ __launch_bounds__(512) void attn2_kernel(
    const _Float16* __restrict__ qh, const _Float16* __restrict__ vh,
    const _Float16* __restrict__ kvg, const float* __restrict__ zg,
    const float* __restrict__ dwc_w, const float* __restrict__ dwc_b,
    _Float16* __restrict__ fused) {
    __shared__ _Float16 q_l[208 * LDK];
    __shared__ _Float16 v_n[196 * 64];

    int bh = blockIdx.x;
    int bb = bh / 12, hh = bh - bb * 12;
    int tid = threadIdx.x;
    int lane = tid & 63, wave = tid >> 6;
    int l15 = lane & 15, l4 = lane >> 4;
    size_t base = (size_t)bh * 12544;

    // zero q pad rows [196,208)
    for (int i = tid; i < 432; i += 512) ((unsigned int*)(q_l + 196 * LDK))[i] = 0u;
    for (int j = tid; j < 3136; j += 512) {
        int e = j * 4, n = e >> 6, c = e & 63;
        *(half4_t*)(q_l + n * LDK + c) = *(const half4_t*)(qh + base + e);
        *(half4_t*)(v_n + e) = *(const half4_t*)(vh + base + e);
    }
    __syncthreads();

    for (int t = wave; t < 52; t += 8) {
        int mt = t >> 2, dt = t & 3;
        int d = dt * 16 + l15;
        f32x4 acc = {0.f, 0.f, 0.f, 0.f};
        half8_t a0 = *(const half8_t*)(q_l + (mt * 16 + l15) * LDK + l4 * 8);
        half8_t a1 = *(const half8_t*)(q_l + (mt * 16 + l15) * LDK + 32 + l4 * 8);
        half8_t b0 = *(const half8_t*)(kvg + (size_t)bh * 4096 + d * 64 + l4 * 8);
        half8_t b1 = *(const half8_t*)(kvg + (size_t)bh * 4096 + d * 64 + 32 + l4 * 8);
        acc = MFMA16(a0, b0, acc);
        acc = MFMA16(a1, b1, acc);

        float bd = dwc_b[d];
        float wc[25];
        #pragma unroll
        for (int j2 = 0; j2 < 25; ++j2) wc[j2] = dwc_w[d * 25 + j2];

        #pragma unroll
        for (int r = 0; r < 4; ++r) {
            int i = mt * 16 + l4 * 4 + r;
            if (i < 196) {
                int y = i / 14, x2 = i - y * 14;
                float cacc = bd;
                #pragma unroll
                for (int ky = 0; ky < 5; ++ky) {
                    int yy = y + ky - 2;
                    bool oky = (unsigned)yy < 14u;
                    #pragma unroll
                    for (int kx = 0; kx < 5; ++kx) {
                        int xx = x2 + kx - 2;
                        if (oky && (unsigned)xx < 14u)
                            cacc += (float)v_n[(yy * 14 + xx) * 64 + d] * wc[ky * 5 + kx];
                    }
                }
                float res = acc[r] * zg[(size_t)bh * 196 + i] + cacc;
                fused[((size_t)bb * 196 + i) * 768 + hh * 64 + d] = (_Float16)res;
            }
        }
    }
}

// ---------------- launcher ----------------

extern "C" void kernel_launch(void* const* d_in, const int* in_sizes, int n_in,
                              void* d_out, int out_size, void* d_ws, size_t ws_size,
                              hipStream_t stream) {
    const float* x       = (const float*)d_in[0];
    const float* w_qkv   = (const float*)d_in[1];
    const float* pos_enc = (const float*)d_in[2];
    const float* dwc_w   = (const float*)d_in[3];
    const float* dwc_b   = (const float*)d_in[4];
    const float* w_proj  = (const float*)d_in[5];
    const float* b_proj  = (const float*)d_in[6];

    const size_t NEEDED = 340574208;
    if (ws_size < NEEDED) return;  // insufficient scratch; bail (output stays poisoned)

    char* ws = (char*)d_ws;
    _Float16* xh     = (_Float16*)(ws + 0);          // 77,070,336 B (also 'fused' later)
    _Float16* fused  = xh;
    _Float16* wqkvT  = (_Float16*)(ws + 77070336);   // 3,538,944
    _Float16* wprojT = (_Float16*)(ws + 80609280);   // 1,179,648
    _Float16* qh     = (_Float16*)(ws + 81788928);   // 77,070,336
    _Float16* kh     = (_Float16*)(ws + 158859264);  // 77,070,336
    _Float16* vh     = (_Float16*)(ws + 235929600);  // 77,070,336
    _Float16* kvg    = (_Float16*)(ws + 312999936);  // 25,165,824
    float*    zg     = (float*)(ws + 338165760);     // 2,408,448

    cvt_f2h_kernel<<<4096, 256, 0, stream>>>(x, xh, 9633792);
    transpose768_kernel<<<(2304 * 768 + 255) / 256, 256, 0, stream>>>(w_qkv, wqkvT, 2304);
    transpose768_kernel<<<(768 * 768 + 255) / 256, 256, 0, stream>>>(w_proj, wprojT, 768);
    gemm_qkv_kernel<<<196 * 9, 512, 0, stream>>>(xh, wqkvT, pos_enc, qh, kh, vh);
    attn1_kernel<<<3072, 512, 0, stream>>>(qh, kh, vh, kvg, zg);
    attn2_kernel<<<3072, 512, 0, stream>>>(qh, vh, kvg, zg, dwc_w, dwc_b, fused);
    gemm_proj_kernel<<<196 * 3, 512, 0, stream>>>(fused, wprojT, b_proj, (float*)d_out);
}

// Round 7
// 730.304 us; speedup vs baseline: 1.1708x; 1.0217x over previous
//
#include <hip/hip_runtime.h>

typedef _Float16 half8_t __attribute__((ext_vector_type(8)));
typedef _Float16 half4_t __attribute__((ext_vector_type(4)));
typedef float f32x4 __attribute__((ext_vector_type(4)));

#define MFMA16(a, b, c) __builtin_amdgcn_mfma_f32_16x16x32_f16((a), (b), (c), 0, 0, 0)

typedef const unsigned int __attribute__((address_space(1)))* gas_ptr;
typedef unsigned int __attribute__((address_space(3)))* las_ptr;

__device__ __forceinline__ void gload16(const void* g, void* l) {
    __builtin_amdgcn_global_load_lds((gas_ptr)g, (las_ptr)l, 16, 0, 0);
}

// m204 bijective XCD swizzle: contiguous wgid chunk per XCD (works for nwg % 8 != 0)
__device__ __forceinline__ int xcd_swizzle(int bid, int nwg) {
    int xcd = bid & 7, i = bid >> 3;
    int q = nwg >> 3, r = nwg & 7;
    return (xcd < r ? xcd * (q + 1) : r * (q + 1) + (xcd - r) * q) + i;
}

// ---------------- convert / transpose ----------------

__global__ void cvt_f2h_kernel(const float* __restrict__ in, _Float16* __restrict__ out, int n4) {
    int stride = gridDim.x * blockDim.x;
    for (int i = blockIdx.x * blockDim.x + threadIdx.x; i < n4; i += stride) {
        f32x4 v = *(const f32x4*)(in + (size_t)4 * i);
        half4_t h;
        h[0] = (_Float16)v[0]; h[1] = (_Float16)v[1];
        h[2] = (_Float16)v[2]; h[3] = (_Float16)v[3];
        *(half4_t*)(out + (size_t)4 * i) = h;
    }
}

// out[j][k] = in[k][j], K fixed at 768
__global__ void transpose768_kernel(const float* __restrict__ in, _Float16* __restrict__ out, int ncols) {
    int idx = blockIdx.x * 256 + threadIdx.x;
    int total = ncols * 768;
    if (idx < total) {
        int j = idx / 768;
        int k = idx - j * 768;
        out[idx] = (_Float16)in[(size_t)k * ncols + j];
    }
}

// ---------------- GEMM core: 256x256 tile, BK=64, 8 waves, 4-phase/K-tile pipeline ----
// A: [M][768] f16 (K contiguous); Bt: [Nout][768] f16 (K contiguous)
// LDS (elements): [parity][op][khalf][256 rows][32 k] = 2*2*2*8192 f16 = 128 KiB.
// Staging half = one op, 256 rows x 32 k (16 KiB) = 2 gload16/thread; dest linear.
// Swizzle (rule #21 both-sides): LDS[r][slot s] = G[r][s ^ ((r>>1)&3)] via pre-swizzled
// global source k-offset ((tid&3) ^ ((tid>>3)&3)); read slot = l4 ^ ((l15>>1)&3)
// -> 2 lanes/bank = free (m136).
// Phase = { ds_read frags ; issue 1 stage ; barrier ; lgkmcnt(0)+sched_barrier ;
//           setprio(1) 16 MFMA setprio(0) ; [vmcnt(N)] ; barrier }.
// PUBLISH RULE (fixes R6 race): data is only ds_read AFTER a barrier that every wave
// reached having already done vmcnt covering its own staging loads of that chunk.
// vmcnt(4) sits before the ending barrier of P1 (publishes this tile's h1 chunks)
// and P3 (publishes next tile's h0 chunks); vmcnt(0) only at final tile's P1 (T4).

#define STAGEH(sp, opn, h, kofe)                                                  \
    {                                                                             \
        const _Float16* gs = (opn) ? Brow : Arow;                                 \
        _Float16* ld = lds + (sp) * 32768 + (opn) * 16384 + (h) * 8192 + wave * 512; \
        gload16(gs + (kofe) + (h) * 32, ld);                                      \
        gload16(gs + (kofe) + (h) * 32 + 98304, ld + 4096);                       \
    }

#define PHASE(par, kk, nh, LOADA, DOSTG, sp, sop, sh, skofe, VMEND)               \
    {                                                                             \
        const _Float16* Ac = lds + (par) * 32768 + (kk) * 8192;                   \
        const _Float16* Bc = Ac + 16384;                                          \
        if (LOADA) {                                                              \
            _Pragma("unroll")                                                     \
            for (int mi = 0; mi < 8; ++mi)                                        \
                afr[mi] = *(const half8_t*)(Ac + (wr * 128 + mi * 16 + l15) * 32 + rsw); \
        }                                                                         \
        bfr[0] = *(const half8_t*)(Bc + (wc * 64 + (nh) * 32 + l15) * 32 + rsw);  \
        bfr[1] = *(const half8_t*)(Bc + (wc * 64 + (nh) * 32 + 16 + l15) * 32 + rsw); \
        if (DOSTG) STAGEH(sp, sop, sh, skofe)                                     \
        __builtin_amdgcn_s_barrier();                                             \
        asm volatile("s_waitcnt lgkmcnt(0)" ::: "memory");                        \
        __builtin_amdgcn_sched_barrier(0);                                        \
        __builtin_amdgcn_s_setprio(1);                                            \
        _Pragma("unroll")                                                         \
        for (int mi = 0; mi < 8; ++mi) {                                          \
            acc[mi][(nh) * 2]     = MFMA16(afr[mi], bfr[0], acc[mi][(nh) * 2]);   \
            acc[mi][(nh) * 2 + 1] = MFMA16(afr[mi], bfr[1], acc[mi][(nh) * 2 + 1]); \
        }                                                                         \
        __builtin_amdgcn_s_setprio(0);                                            \
        if ((VMEND) >= 0)                                                         \
            asm volatile("s_waitcnt vmcnt(%0)" :: "i"(VMEND) : "memory");         \
        __builtin_amdgcn_s_barrier();                                             \
    }

__device__ __forceinline__ void run_gemm256(const _Float16* __restrict__ A,
                                            const _Float16* __restrict__ Bt,
                                            int mbase, int nbase,
                                            _Float16* lds,          // 65536 f16
                                            f32x4 (&acc)[8][4]) {
    const int tid = threadIdx.x;
    const int lane = tid & 63;
    const int wave = tid >> 6;
    const int wr = wave >> 2;        // 0..1  (M half)
    const int wc = wave & 3;         // 0..3  (N quarter)
    const int l15 = lane & 15;
    const int l4 = lane >> 4;
    const int fx = (l15 >> 1) & 3;               // read swizzle key (2-way = free)
    const int rsw = (l4 ^ fx) << 3;              // read k-slot elem offset
    const int ksw = ((tid & 3) ^ ((tid >> 3) & 3)) << 3;  // staging source pre-swizzle

    #pragma unroll
    for (int mi = 0; mi < 8; ++mi)
        #pragma unroll
        for (int ni = 0; ni < 4; ++ni)
            acc[mi][ni] = (f32x4){0.f, 0.f, 0.f, 0.f};

    // per-thread staging source base: row = (tid>>2) (+128 for 2nd gload), k pre-swizzled
    const _Float16* Arow = A + (size_t)(mbase + (tid >> 2)) * 768 + ksw;
    const _Float16* Brow = Bt + (size_t)(nbase + (tid >> 2)) * 768 + ksw;

    half8_t afr[8], bfr[2];

    // prologue: stage tile 0's halves (issue order = steady-state age order),
    // then publish h0 chunks: every wave waits its own 4 oldest, then barrier.
    STAGEH(0, 0, 0, 0)   // A(0,h0)
    STAGEH(0, 1, 0, 0)   // B(0,h0)
    STAGEH(0, 0, 1, 0)   // A(0,h1)
    STAGEH(0, 1, 1, 0)   // B(0,h1)
    asm volatile("s_waitcnt vmcnt(4)" ::: "memory");
    __builtin_amdgcn_s_barrier();

    // K-tiles 0..9 (pairs): tile t (par=t&1) stages tile t+1 into slot (t+1)&1
    for (int it = 0; it < 5; ++it) {
        const int kofa = (2 * it + 1) * 64;
        PHASE(0, 0, 0, true,  true, 1, 0, 0, kofa, -1)
        PHASE(0, 0, 1, false, true, 1, 1, 0, kofa,  4)   // publish (t,h1)
        PHASE(0, 1, 0, true,  true, 1, 0, 1, kofa, -1)
        PHASE(0, 1, 1, false, true, 1, 1, 1, kofa,  4)   // publish (t+1,h0)
        const int kofb = (2 * it + 2) * 64;
        PHASE(1, 0, 0, true,  true, 0, 0, 0, kofb, -1)
        PHASE(1, 0, 1, false, true, 0, 1, 0, kofb,  4)
        PHASE(1, 1, 0, true,  true, 0, 0, 1, kofb, -1)
        PHASE(1, 1, 1, false, true, 0, 1, 1, kofb,  4)
    }
    // K-tile 10 (par 0): stages tile 11 into slot 1
    {
        const int kofa = 11 * 64;
        PHASE(0, 0, 0, true,  true, 1, 0, 0, kofa, -1)
        PHASE(0, 0, 1, false, true, 1, 1, 0, kofa,  4)
        PHASE(0, 1, 0, true,  true, 1, 0, 1, kofa, -1)
        PHASE(0, 1, 1, false, true, 1, 1, 1, kofa,  4)
    }
    // K-tile 11 (par 1): tail — no staging; drain remaining 4 loads at P1
    PHASE(1, 0, 0, true,  false, 0, 0, 0, 0, -1)
    PHASE(1, 0, 1, false, false, 0, 0, 0, 0,  0)   // publish (11,h1), full drain
    PHASE(1, 1, 0, true,  false, 0, 0, 0, 0, -1)
    PHASE(1, 1, 1, false, false, 0, 0, 0, 0, -1)
}

// GEMM1: qkv = x @ w_qkv, epilogue: +pos_enc (k), relu (q,k), scatter to head layout
__global__ __launch_bounds__(512, 2) void gemm_qkv_kernel(
    const _Float16* __restrict__ xh, const _Float16* __restrict__ wqkvT,
    const float* __restrict__ pos_enc,
    _Float16* __restrict__ qh, _Float16* __restrict__ kh, _Float16* __restrict__ vh) {
    __shared__ _Float16 lds[2 * 2 * 2 * 8192];
    // XCD-grouped: 9 consecutive wgids (one mtile's ntiles) land on one XCD -> A panel L2-shared
    int wgid = xcd_swizzle(blockIdx.x, 196 * 9);
    int mtile = wgid / 9, ntile = wgid - mtile * 9;
    f32x4 acc[8][4];
    run_gemm256(xh, wqkvT, mtile * 256, ntile * 256, lds, acc);

    const int tid = threadIdx.x;
    const int lane = tid & 63;
    const int wave = tid >> 6;
    const int wr = wave >> 2;
    const int wc = wave & 3;
    const int l15 = lane & 15;
    const int l4 = lane >> 4;

    // 768 = 3*256: all 256 columns of this block live in one q/k/v segment
    const int s = ntile / 3;
    const int cb = (ntile - s * 3) * 256 + wc * 64;
    _Float16* dst = (s == 0) ? qh : ((s == 1) ? kh : vh);

    #pragma unroll
    for (int mi = 0; mi < 8; ++mi) {
        #pragma unroll
        for (int ni = 0; ni < 4; ++ni) {
            int c = cb + ni * 16 + l15;
            int h = c >> 6, d = c & 63;
            #pragma unroll
            for (int r = 0; r < 4; ++r) {
                int gr = mtile * 256 + wr * 128 + mi * 16 + l4 * 4 + r;
                int b = gr / 196;
                int n = gr - b * 196;
                float v = acc[mi][ni][r];
                if (s == 1) v += pos_enc[n * 768 + c];
                if (s < 2) v = fmaxf(v, 0.f);
                dst[((size_t)(b * 12 + h) * 196 + n) * 64 + d] = (_Float16)v;
            }
        }
    }
}

// GEMM2: out = fused @ w_proj + b_proj (f32 out)
__global__ __launch_bounds__(512, 2) void gemm_proj_kernel(
    const _Float16* __restrict__ fused, const _Float16* __restrict__ wprojT,
    const float* __restrict__ b_proj, float* __restrict__ out) {
    __shared__ _Float16 lds[2 * 2 * 2 * 8192];
    int wgid = xcd_swizzle(blockIdx.x, 196 * 3);
    int mtile = wgid / 3, ntile = wgid - mtile * 3;
    f32x4 acc[8][4];
    run_gemm256(fused, wprojT, mtile * 256, ntile * 256, lds, acc);

    const int tid = threadIdx.x;
    const int lane = tid & 63;
    const int wave = tid >> 6;
    const int wr = wave >> 2;
    const int wc = wave & 3;
    const int l15 = lane & 15;
    const int l4 = lane >> 4;

    #pragma unroll
    for (int mi = 0; mi < 8; ++mi) {
        #pragma unroll
        for (int ni = 0; ni < 4; ++ni) {
            int gc = ntile * 256 + wc * 64 + ni * 16 + l15;
            float bp = b_proj[gc];
            #pragma unroll
            for (int r = 0; r < 4; ++r) {
                int gr = mtile * 256 + wr * 128 + mi * 16 + l4 * 4 + r;
                out[(size_t)gr * 768 + gc] = acc[mi][ni][r] + bp;
            }
        }
    }
}

// ---------------- attention part 1: kv = k^T v (64x64), ksum, z ----------------
__global__ __launch_bounds__(512) void attn1_kernel(
    const _Float16* __restrict__ qh, const _Float16* __restrict__ kh,
    const _Float16* __restrict__ vh, _Float16* __restrict__ kvg, float* __restrict__ zg) {
    __shared__ _Float16 k_t[64 * 232];
    __shared__ _Float16 v_t[64 * 232];
    __shared__ float ksum_p[8 * 64];
    __shared__ float ksum[64];

    int bh = blockIdx.x;
    int tid = threadIdx.x;
    int lane = tid & 63, wave = tid >> 6;
    int l15 = lane & 15, l4 = lane >> 4;
    size_t base = (size_t)bh * 12544;

    // zero pad columns [196,232)
    for (int idx = tid; idx < 1152; idx += 512) {
        int c = idx / 18, u = idx - c * 18;
        ((unsigned int*)(k_t + c * 232 + 196))[u] = 0u;
        ((unsigned int*)(v_t + c * 232 + 196))[u] = 0u;
    }
    // load + transpose k, v
    for (int j = tid; j < 3136; j += 512) {
        int e = j * 4, n = e >> 6, c = e & 63;
        half4_t kq = *(const half4_t*)(kh + base + e);
        half4_t vq = *(const half4_t*)(vh + base + e);
        k_t[(c + 0) * 232 + n] = kq[0]; k_t[(c + 1) * 232 + n] = kq[1];
        k_t[(c + 2) * 232 + n] = kq[2]; k_t[(c + 3) * 232 + n] = kq[3];
        v_t[(c + 0) * 232 + n] = vq[0]; v_t[(c + 1) * 232 + n] = vq[1];
        v_t[(c + 2) * 232 + n] = vq[2]; v_t[(c + 3) * 232 + n] = vq[3];
    }
    __syncthreads();

    // kv MFMA: wave -> (ct, dt0), (ct, dt0+1)
    int ct = wave >> 1, dt0 = (wave & 1) * 2;
    f32x4 acc0 = {0.f, 0.f, 0.f, 0.f}, acc1 = {0.f, 0.f, 0.f, 0.f};
    #pragma unroll
    for (int ks = 0; ks < 7; ++ks) {
        half8_t a  = *(const half8_t*)(k_t + (ct * 16 + l15) * 232 + ks * 32 + l4 * 8);
        half8_t b0 = *(const half8_t*)(v_t + (dt0 * 16 + l15) * 232 + ks * 32 + l4 * 8);
        half8_t b1 = *(const half8_t*)(v_t + (dt0 * 16 + 16 + l15) * 232 + ks * 32 + l4 * 8);
        acc0 = MFMA16(a, b0, acc0);
        acc1 = MFMA16(a, b1, acc1);
    }
    {
        half4_t h0, h1;
        #pragma unroll
        for (int r = 0; r < 4; ++r) { h0[r] = (_Float16)acc0[r]; h1[r] = (_Float16)acc1[r]; }
        // store kv transposed: kvg[d][c]
        *(half4_t*)(kvg + (size_t)bh * 4096 + (dt0 * 16 + l15) * 64 + ct * 16 + l4 * 4) = h0;
        *(half4_t*)(kvg + (size_t)bh * 4096 + ((dt0 + 1) * 16 + l15) * 64 + ct * 16 + l4 * 4) = h1;
    }
    // ksum partials
    {
        int n0 = wave * 25;
        int n1 = (n0 + 25 < 196) ? (n0 + 25) : 196;
        float s = 0.f;
        for (int n = n0; n < n1; ++n) s += (float)k_t[lane * 232 + n];
        ksum_p[wave * 64 + lane] = s;
    }
    __syncthreads();
    if (tid < 64) {
        float s = 0.f;
        #pragma unroll
        for (int w = 0; w < 8; ++w) s += ksum_p[w * 64 + tid];
        ksum[tid] = s;
    }
    __syncthreads();
    if (tid < 196) {
        const _Float16* qrow = qh + base + tid * 64;
        float s = 0.f;
        #pragma unroll
        for (int c = 0; c < 64; ++c) s += (float)qrow[c] * ksum[c];
        zg[(size_t)bh * 196 + tid] = 1.0f / (s + 1e-6f);
    }
}

// ---------------- attention part 2: out = z*(q@kv) + dwconv(v), write fused ----------------
#define LDK 72
__global__ __launch_bounds__(512) void attn2_kernel(
    const _Float16* __restrict__ qh, const _Float16* __restrict__ vh,
    const _Float16* __restrict__ kvg, const float* __restrict__ zg,
    const float* __restrict__ dwc_w, const float* __restrict__ dwc_b,
    _Float16* __restrict__ fused) {
    __shared__ _Float16 q_l[208 * LDK];
    __shared__ _Float16 v_n[196 * 64];

    int bh = blockIdx.x;
    int bb = bh / 12, hh = bh - bb * 12;
    int tid = threadIdx.x;
    int lane = tid & 63, wave = tid >> 6;
    int l15 = lane & 15, l4 = lane >> 4;
    size_t base = (size_t)bh * 12544;

    // zero q pad rows [196,208)
    for (int i = tid; i < 432; i += 512) ((unsigned int*)(q_l + 196 * LDK))[i] = 0u;
    for (int j = tid; j < 3136; j += 512) {
        int e = j * 4, n = e >> 6, c = e & 63;
        *(half4_t*)(q_l + n * LDK + c) = *(const half4_t*)(qh + base + e);
        *(half4_t*)(v_n + e) = *(const half4_t*)(vh + base + e);
    }
    __syncthreads();

    for (int t = wave; t < 52; t += 8) {
        int mt = t >> 2, dt = t & 3;
        int d = dt * 16 + l15;
        f32x4 acc = {0.f, 0.f, 0.f, 0.f};
        half8_t a0 = *(const half8_t*)(q_l + (mt * 16 + l15) * LDK + l4 * 8);
        half8_t a1 = *(const half8_t*)(q_l + (mt * 16 + l15) * LDK + 32 + l4 * 8);
        half8_t b0 = *(const half8_t*)(kvg + (size_t)bh * 4096 + d * 64 + l4 * 8);
        half8_t b1 = *(const half8_t*)(kvg + (size_t)bh * 4096 + d * 64 + 32 + l4 * 8);
        acc = MFMA16(a0, b0, acc);
        acc = MFMA16(a1, b1, acc);

        float bd = dwc_b[d];
        float wc[25];
        #pragma unroll
        for (int j2 = 0; j2 < 25; ++j2) wc[j2] = dwc_w[d * 25 + j2];

        #pragma unroll
        for (int r = 0; r < 4; ++r) {
            int i = mt * 16 + l4 * 4 + r;
            if (i < 196) {
                int y = i / 14, x2 = i - y * 14;
                float cacc = bd;
                #pragma unroll
                for (int ky = 0; ky < 5; ++ky) {
                    int yy = y + ky - 2;
                    bool oky = (unsigned)yy < 14u;
                    #pragma unroll
                    for (int kx = 0; kx < 5; ++kx) {
                        int xx = x2 + kx - 2;
                        if (oky && (unsigned)xx < 14u)
                            cacc += (float)v_n[(yy * 14 + xx) * 64 + d] * wc[ky * 5 + kx];
                    }
                }
                float res = acc[r] * zg[(size_t)bh * 196 + i] + cacc;
                fused[((size_t)bb * 196 + i) * 768 + hh * 64 + d] = (_Float16)res;
            }
        }
    }
}

// ---------------- launcher ----------------

extern "C" void kernel_launch(void* const* d_in, const int* in_sizes, int n_in,
                              void* d_out, int out_size, void* d_ws, size_t ws_size,
                              hipStream_t stream) {
    const float* x       = (const float*)d_in[0];
    const float* w_qkv   = (const float*)d_in[1];
    const float* pos_enc = (const float*)d_in[2];
    const float* dwc_w   = (const float*)d_in[3];
    const float* dwc_b   = (const float*)d_in[4];
    const float* w_proj  = (const float*)d_in[5];
    const float* b_proj  = (const float*)d_in[6];

    const size_t NEEDED = 340574208;
    if (ws_size < NEEDED) return;  // insufficient scratch; bail (output stays poisoned)

    char* ws = (char*)d_ws;
    _Float16* xh     = (_Float16*)(ws + 0);          // 77,070,336 B (also 'fused' later)
    _Float16* fused  = xh;
    _Float16* wqkvT  = (_Float16*)(ws + 77070336);   // 3,538,944
    _Float16* wprojT = (_Float16*)(ws + 80609280);   // 1,179,648
    _Float16* qh     = (_Float16*)(ws + 81788928);   // 77,070,336
    _Float16* kh     = (_Float16*)(ws + 158859264);  // 77,070,336
    _Float16* vh     = (_Float16*)(ws + 235929600);  // 77,070,336
    _Float16* kvg    = (_Float16*)(ws + 312999936);  // 25,165,824
    float*    zg     = (float*)(ws + 338165760);     // 2,408,448

    cvt_f2h_kernel<<<4096, 256, 0, stream>>>(x, xh, 9633792);
    transpose768_kernel<<<(2304 * 768 + 255) / 256, 256, 0, stream>>>(w_qkv, wqkvT, 2304);
    transpose768_kernel<<<(768 * 768 + 255) / 256, 256, 0, stream>>>(w_proj, wprojT, 768);
    gemm_qkv_kernel<<<196 * 9, 512, 0, stream>>>(xh, wqkvT, pos_enc, qh, kh, vh);
    attn1_kernel<<<3072, 512, 0, stream>>>(qh, kh, vh, kvg, zg);
    attn2_kernel<<<3072, 512, 0, stream>>>(qh, vh, kvg, zg, dwc_w, dwc_b, fused);
    gemm_proj_kernel<<<196 * 3, 512, 0, stream>>>(fused, wprojT, b_proj, (float*)d_out);
}